// Round 4
// baseline (127.348 us; speedup 1.0000x reference)
//
#include <hip/hip_runtime.h>

// HyperLinear, fused + pipelined:
//   setup_kernel: build Bb[832][256] bf16 (512 permuted fcwp_w rows, 64 c-rows,
//                 256 target_w rows) via coalesced LDS transposes, and
//                 B2[256][96] bf16 (fcwe_w | fcbp_w | fcwe_b | bias_const | 0).
//   fused_kernel (128 blocks x 16 samples):
//     GEMM1: x_bf @ Bb^T consumed tile-by-tile with double-buffered LDS +
//       register prefetch (1 barrier/tile):
//       tiles 0..7  -> t[s][m] via per-lane h-scale + shfl_xor p-reduction
//       tile  8     -> t += c-part (1 extra barrier)
//       tiles 9..12 -> ybase fragments (x @ target_w^T) kept in regs
//     GEMM2: out = ybase + [t | h | sx | 1 | 0] @ B2^T  (K=96, 12 MFMAs/wave)

#define B_TOT 2048
#define NP    8
#define CIN   256
#define COUT  256
#define MID   64
#define LDA   264    // As row stride (bf16)
#define LDB   264    // Bs row stride (bf16)
#define LDT   72     // t row stride (fp32)
#define LDA2  104    // A2 row stride (bf16)

typedef short  short8  __attribute__((ext_vector_type(8)));
typedef float  floatx4 __attribute__((ext_vector_type(4)));

__device__ __forceinline__ unsigned short f2bf(float f) {
    union { float f; unsigned u; } v; v.f = f;
    unsigned r = v.u + 0x7FFFu + ((v.u >> 16) & 1u);
    return (unsigned short)(r >> 16);
}
__device__ __forceinline__ float bf2f(unsigned short u) {
    union { unsigned u; float f; } v; v.u = ((unsigned)u) << 16;
    return v.f;
}

// ---------------- setup ----------------
__global__ __launch_bounds__(256) void setup_kernel(
    const float* __restrict__ index,
    const float* __restrict__ target_w, const float* __restrict__ target_b,
    const float* __restrict__ fcwp_w, const float* __restrict__ fcwp_b,
    const float* __restrict__ fcwi_w, const float* __restrict__ fcwi_b,
    const float* __restrict__ fcwe_w, const float* __restrict__ fcwe_b,
    const float* __restrict__ fcbp_w, const float* __restrict__ fcbp_b,
    const float* __restrict__ fcbi_w, const float* __restrict__ fcbi_b,
    unsigned short* __restrict__ Bb, unsigned short* __restrict__ B2)
{
    __shared__ unsigned short Lt[64][68];
    const int blk = blockIdx.x, tid = threadIdx.x;

    if (blk < 32) {
        // Bb[n][i] = bf16(fcwp_w[i*512+n]); 64x64 tile transpose
        const int i0 = (blk >> 3) * 64, n0 = (blk & 7) * 64;
        const int r = tid >> 4, c4 = (tid & 15) * 4;
        #pragma unroll
        for (int k = 0; k < 4; ++k) {
            int ii = r + k * 16;
            float4 v = *(const float4*)(fcwp_w + (size_t)(i0 + ii) * 512 + n0 + c4);
            Lt[c4 + 0][ii] = f2bf(v.x); Lt[c4 + 1][ii] = f2bf(v.y);
            Lt[c4 + 2][ii] = f2bf(v.z); Lt[c4 + 3][ii] = f2bf(v.w);
        }
        __syncthreads();
        const int nn = tid >> 2, ic0 = (tid & 3) * 16;
        #pragma unroll
        for (int k = 0; k < 4; ++k) {
            int ic = ic0 + k * 4;
            ushort4 o4;
            o4.x = Lt[nn][ic]; o4.y = Lt[nn][ic + 1];
            o4.z = Lt[nn][ic + 2]; o4.w = Lt[nn][ic + 3];
            *(ushort4*)&Bb[(size_t)(n0 + nn) * CIN + i0 + ic] = o4;
        }
    } else if (blk < 36) {
        // c rows: Bb[512+m][i] = bf16(fcwp_b[e]+fcwi_b[e]+index·fcwi_w[e,:]), e=i*64+m
        const int i0 = (blk - 32) * 64;
        const float x0 = index[0], x1 = index[1], x2 = index[2], x3 = index[3];
        const int r = tid >> 4, c4 = (tid & 15) * 4;
        #pragma unroll
        for (int k = 0; k < 4; ++k) {
            int ii = r + k * 16;
            int e = (i0 + ii) * 64 + c4;
            float4 pb = *(const float4*)(fcwp_b + e);
            float4 ib = *(const float4*)(fcwi_b + e);
            float pbv[4] = {pb.x, pb.y, pb.z, pb.w};
            float ibv[4] = {ib.x, ib.y, ib.z, ib.w};
            #pragma unroll
            for (int j = 0; j < 4; ++j) {
                float4 wv = *(const float4*)(fcwi_w + (size_t)(e + j) * 4);
                float val = pbv[j] + ibv[j]
                          + x0 * wv.x + x1 * wv.y + x2 * wv.z + x3 * wv.w;
                Lt[c4 + j][ii] = f2bf(val);
            }
        }
        __syncthreads();
        const int mm = tid >> 2, ic0 = (tid & 3) * 16;
        #pragma unroll
        for (int k = 0; k < 4; ++k) {
            int ic = ic0 + k * 4;
            ushort4 o4;
            o4.x = Lt[mm][ic]; o4.y = Lt[mm][ic + 1];
            o4.z = Lt[mm][ic + 2]; o4.w = Lt[mm][ic + 3];
            *(ushort4*)&Bb[(size_t)(512 + mm) * CIN + i0 + ic] = o4;
        }
    } else if (blk < 52) {
        // target_w rows [576,832): straight convert-copy (65536 elems)
        #pragma unroll
        for (int k = 0; k < 4; ++k) {
            int e = (blk - 36) * 4096 + k * 1024 + tid * 4;
            float4 v = *(const float4*)(target_w + e);
            ushort4 o4;
            o4.x = f2bf(v.x); o4.y = f2bf(v.y); o4.z = f2bf(v.z); o4.w = f2bf(v.w);
            *(ushort4*)&Bb[(size_t)576 * CIN + e] = o4;
        }
    } else if (blk < 68) {
        // B2 cols 0..63 = fcwe_w (16384 elems)
        int e = (blk - 52) * 1024 + tid * 4;
        int o = e >> 6, m = e & 63;
        float4 v = *(const float4*)(fcwe_w + e);
        ushort4 o4;
        o4.x = f2bf(v.x); o4.y = f2bf(v.y); o4.z = f2bf(v.z); o4.w = f2bf(v.w);
        *(ushort4*)&B2[(size_t)o * 96 + m] = o4;
    } else {
        // B2 tail per output o
        int o = tid;
        float4 p0 = *(const float4*)(fcbp_w + (size_t)o * 8);
        float4 p1 = *(const float4*)(fcbp_w + (size_t)o * 8 + 4);
        B2[o * 96 + 64] = f2bf(p0.x); B2[o * 96 + 65] = f2bf(p0.y);
        B2[o * 96 + 66] = f2bf(p0.z); B2[o * 96 + 67] = f2bf(p0.w);
        B2[o * 96 + 68] = f2bf(p1.x); B2[o * 96 + 69] = f2bf(p1.y);
        B2[o * 96 + 70] = f2bf(p1.z); B2[o * 96 + 71] = f2bf(p1.w);
        B2[o * 96 + 72] = f2bf(fcwe_b[o]);
        float bc = target_b[o] + fcbp_b[o] + fcbi_b[o]
                 + index[0] * fcbi_w[o * 4]     + index[1] * fcbi_w[o * 4 + 1]
                 + index[2] * fcbi_w[o * 4 + 2] + index[3] * fcbi_w[o * 4 + 3];
        B2[o * 96 + 73] = f2bf(bc);
        #pragma unroll
        for (int z = 74; z < 96; ++z) B2[o * 96 + z] = 0;
    }
}

// ---------------- fused GEMM + epilogue (pipelined) ----------------
__global__ __launch_bounds__(256) void fused_kernel(
    const float* __restrict__ x,              // [2048][256]
    const float* __restrict__ h,              // [2048][8]
    const unsigned short* __restrict__ Bb,    // [832][256] bf16
    const unsigned short* __restrict__ B2,    // [256][96]  bf16
    float* __restrict__ out)                  // [2048][256]
{
    __shared__ unsigned short As[16 * LDA];       // 8448 B
    __shared__ unsigned short Bs[2][64 * LDB];    // 67584 B
    __shared__ float tl[16][LDT];                 // 4608 B
    __shared__ float hl[16][NP];
    __shared__ float ps[16][16];
    __shared__ float sxl[16];
    __shared__ unsigned short A2[16 * LDA2];      // 3328 B

    const int tid  = threadIdx.x;
    const int lane = tid & 63, w = tid >> 6;
    const int col  = lane & 15, quad = lane >> 4;
    const int b0   = blockIdx.x * 16;

    // stage As (x -> bf16)
    #pragma unroll
    for (int it = 0; it < 4; ++it) {
        int idx = it * 256 + tid;
        int r = idx >> 6, c = (idx & 63) * 4;
        float4 v = *(const float4*)(x + (size_t)(b0 + r) * CIN + c);
        ushort4 o4;
        o4.x = f2bf(v.x); o4.y = f2bf(v.y); o4.z = f2bf(v.z); o4.w = f2bf(v.w);
        *(ushort4*)&As[r * LDA + c] = o4;
    }
    if (tid < 16 * NP) hl[tid >> 3][tid & 7] = h[(size_t)b0 * NP + tid];
    __syncthreads();

    // per-lane h value for the t-reduction: h[s = quad*4+r][p = col&7]
    float hr[4];
    #pragma unroll
    for (int r = 0; r < 4; ++r) hr[r] = hl[quad * 4 + r][col & 7];

    // sx[s] = sum_i x_bf16[s][i]
    {
        int s = tid >> 4, seg = tid & 15;
        float p = 0.f;
        #pragma unroll
        for (int j = 0; j < 16; ++j) p += bf2f(As[s * LDA + seg * 16 + j]);
        ps[s][seg] = p;
    }
    __syncthreads();
    if (tid < 16) {
        float p = 0.f;
        #pragma unroll
        for (int j = 0; j < 16; ++j) p += ps[tid][j];
        sxl[tid] = p;
    }

    // prefetch tile 0
    uint4 pf[8];
    #pragma unroll
    for (int it = 0; it < 8; ++it) {
        int idx = it * 256 + tid;
        pf[it] = *(const uint4*)(Bb + (size_t)(idx >> 5) * CIN + (idx & 31) * 8);
    }

    floatx4 ybase[4];

    for (int nt = 0; nt < 13; ++nt) {
        unsigned short* bs = Bs[nt & 1];
        #pragma unroll
        for (int it = 0; it < 8; ++it) {
            int idx = it * 256 + tid;
            *(uint4*)&bs[(idx >> 5) * LDB + (idx & 31) * 8] = pf[it];
        }
        if (nt < 12) {   // prefetch next tile; loads overlap this tile's MFMA
            const unsigned short* src = Bb + (size_t)(nt + 1) * 64 * CIN;
            #pragma unroll
            for (int it = 0; it < 8; ++it) {
                int idx = it * 256 + tid;
                pf[it] = *(const uint4*)(src + (size_t)(idx >> 5) * CIN + (idx & 31) * 8);
            }
        }
        __syncthreads();

        floatx4 a0 = floatx4{0.f, 0.f, 0.f, 0.f};
        floatx4 a1 = floatx4{0.f, 0.f, 0.f, 0.f};
        #pragma unroll
        for (int ks = 0; ks < 4; ++ks) {
            int kc0 = ks * 32 + quad * 8;
            int kc1 = 128 + kc0;
            short8 af0 = *(const short8*)&As[col * LDA + kc0];
            short8 bf0 = *(const short8*)&bs[(w * 16 + col) * LDB + kc0];
            a0 = __builtin_amdgcn_mfma_f32_16x16x32_bf16(af0, bf0, a0, 0, 0, 0);
            short8 af1 = *(const short8*)&As[col * LDA + kc1];
            short8 bf1 = *(const short8*)&bs[(w * 16 + col) * LDB + kc1];
            a1 = __builtin_amdgcn_mfma_f32_16x16x32_bf16(af1, bf1, a1, 0, 0, 0);
        }

        if (nt < 8) {
            // t[s][m] = sum_p h[s][p]*Y[s][m*8+p]; p = col&7 across adjacent lanes
            float u[4];
            #pragma unroll
            for (int r = 0; r < 4; ++r) u[r] = (a0[r] + a1[r]) * hr[r];
            #pragma unroll
            for (int r = 0; r < 4; ++r) {
                u[r] += __shfl_xor(u[r], 1);
                u[r] += __shfl_xor(u[r], 2);
                u[r] += __shfl_xor(u[r], 4);
            }
            if ((col & 7) == 0) {
                int m = nt * 8 + 2 * w + (col >> 3);
                #pragma unroll
                for (int r = 0; r < 4; ++r) tl[quad * 4 + r][m] = u[r];
            }
        } else if (nt == 8) {
            __syncthreads();   // make tiles 0-7 t-writes visible across waves
            #pragma unroll
            for (int r = 0; r < 4; ++r)
                tl[quad * 4 + r][w * 16 + col] += a0[r] + a1[r];
        } else {
            floatx4 s;
            #pragma unroll
            for (int r = 0; r < 4; ++r) s[r] = a0[r] + a1[r];
            ybase[nt - 9] = s;
        }
    }
    __syncthreads();

    // build A2 = [t | h | sx | 1 | 0...] (16 x 96, stride LDA2)
    #pragma unroll
    for (int it = 0; it < 4; ++it) {
        int idx = it * 256 + tid;
        int s = idx >> 6, m = idx & 63;
        A2[s * LDA2 + m] = f2bf(tl[s][m]);
    }
    if (tid < 128) A2[(tid >> 3) * LDA2 + 64 + (tid & 7)] = f2bf(hl[tid >> 3][tid & 7]);
    if (tid < 16) {
        A2[tid * LDA2 + 72] = f2bf(sxl[tid]);
        A2[tid * LDA2 + 73] = 0x3F80;   // 1.0 bf16
    }
    for (int idx = tid; idx < 16 * 22; idx += 256) {
        int s = idx / 22, cc = 74 + idx % 22;
        A2[s * LDA2 + cc] = 0;
    }
    __syncthreads();

    // GEMM2: out = ybase + A2 @ B2^T
    floatx4 y2[4];
    #pragma unroll
    for (int j = 0; j < 4; ++j) y2[j] = ybase[j];
    #pragma unroll
    for (int ks = 0; ks < 3; ++ks) {
        int kc = ks * 32 + quad * 8;
        short8 af = *(const short8*)&A2[col * LDA2 + kc];
        #pragma unroll
        for (int j = 0; j < 4; ++j) {
            short8 bf = *(const short8*)(B2 + (size_t)(j * 64 + w * 16 + col) * 96 + kc);
            y2[j] = __builtin_amdgcn_mfma_f32_16x16x32_bf16(af, bf, y2[j], 0, 0, 0);
        }
    }
    #pragma unroll
    for (int j = 0; j < 4; ++j)
        #pragma unroll
        for (int r = 0; r < 4; ++r)
            out[(size_t)(b0 + quad * 4 + r) * COUT + j * 64 + w * 16 + col] = y2[j][r];
}

extern "C" void kernel_launch(void* const* d_in, const int* in_sizes, int n_in,
                              void* d_out, int out_size, void* d_ws, size_t ws_size,
                              hipStream_t stream) {
    const float* x        = (const float*)d_in[0];
    const float* h        = (const float*)d_in[1];
    const float* index    = (const float*)d_in[2];
    const float* target_w = (const float*)d_in[3];
    const float* target_b = (const float*)d_in[4];
    const float* fcwp_w   = (const float*)d_in[5];
    const float* fcwp_b   = (const float*)d_in[6];
    const float* fcwi_w   = (const float*)d_in[7];
    const float* fcwi_b   = (const float*)d_in[8];
    const float* fcwe_w   = (const float*)d_in[9];
    const float* fcwe_b   = (const float*)d_in[10];
    const float* fcbp_w   = (const float*)d_in[11];
    const float* fcbp_b   = (const float*)d_in[12];
    const float* fcbi_w   = (const float*)d_in[13];
    const float* fcbi_b   = (const float*)d_in[14];
    float* out = (float*)d_out;

    char* ws = (char*)d_ws;
    unsigned short* Bb = (unsigned short*)ws;             // 832*256*2 = 425984 B
    unsigned short* B2 = (unsigned short*)(ws + 425984);  // 256*96*2  =  49152 B

    setup_kernel<<<69, 256, 0, stream>>>(
        index, target_w, target_b, fcwp_w, fcwp_b, fcwi_w, fcwi_b,
        fcwe_w, fcwe_b, fcbp_w, fcbp_b, fcbi_w, fcbi_b, Bb, B2);

    fused_kernel<<<B_TOT / 16, 256, 0, stream>>>(x, h, Bb, B2, out);
}

// Round 5
// 93.416 us; speedup vs baseline: 1.3632x; 1.3632x over previous
//
#include <hip/hip_runtime.h>

// HyperLinear, 3-kernel split:
//  setup:  Bb[576][256] bf16 (512 permuted fcwp_w rows + 64 c-rows),
//          B2[256][352] bf16 (target_w | fcwe_w | fcbp_w | fcwe_b | bias_const | 0),
//          A2[2048][352] bf16 (x | <t hole> | h | sx | 1 | 0)  + per-row sx.
//  gemm1:  G[2048][576] bf16 = A2[:,0:256] @ Bb^T          (64x64 tiles, 288 blocks)
//  gemm2:  out[2048][256] f32 = [x|t|h|sx|1] @ B2^T where t is folded from G
//          in the prologue (t[s][m] = sum_p h[s][p]*G[s][m*8+p] + G[s][512+m]).

#define B_TOT 2048
#define NP    8
#define CIN   256
#define COUT  256
#define MID   64
#define NB1   576
#define K2    352    // A2/B2 row stride & GEMM2 K
#define LDG   576    // G row stride (shorts)
#define LDAS  136    // gemm1 LDS row stride
#define LDA2S 360    // gemm2 LDS A row stride (720 B)
#define LDB2S 360    // gemm2 LDS B row stride

typedef short  short8  __attribute__((ext_vector_type(8)));
typedef float  floatx4 __attribute__((ext_vector_type(4)));

__device__ __forceinline__ unsigned short f2bf(float f) {
    union { float f; unsigned u; } v; v.f = f;
    unsigned r = v.u + 0x7FFFu + ((v.u >> 16) & 1u);
    return (unsigned short)(r >> 16);
}
__device__ __forceinline__ float bf2f(unsigned short u) {
    union { unsigned u; float f; } v; v.u = ((unsigned)u) << 16;
    return v.f;
}

// ---------------- setup ----------------
__global__ __launch_bounds__(256) void setup_kernel(
    const float* __restrict__ x, const float* __restrict__ h,
    const float* __restrict__ index,
    const float* __restrict__ target_w, const float* __restrict__ target_b,
    const float* __restrict__ fcwp_w, const float* __restrict__ fcwp_b,
    const float* __restrict__ fcwi_w, const float* __restrict__ fcwi_b,
    const float* __restrict__ fcwe_w, const float* __restrict__ fcwe_b,
    const float* __restrict__ fcbp_w, const float* __restrict__ fcbp_b,
    const float* __restrict__ fcbi_w, const float* __restrict__ fcbi_b,
    unsigned short* __restrict__ Bb, unsigned short* __restrict__ B2,
    unsigned short* __restrict__ A2)
{
    __shared__ unsigned short Lt[64][68];
    __shared__ float red[32][8];
    const int blk = blockIdx.x, tid = threadIdx.x;

    if (blk < 32) {
        // Bb[n][i] = bf16(fcwp_w[i*512+n]); 64x64 tile transpose (verified r3)
        const int i0 = (blk >> 3) * 64, n0 = (blk & 7) * 64;
        const int r = tid >> 4, c4 = (tid & 15) * 4;
        #pragma unroll
        for (int k = 0; k < 4; ++k) {
            int ii = r + k * 16;
            float4 v = *(const float4*)(fcwp_w + (size_t)(i0 + ii) * 512 + n0 + c4);
            Lt[c4 + 0][ii] = f2bf(v.x); Lt[c4 + 1][ii] = f2bf(v.y);
            Lt[c4 + 2][ii] = f2bf(v.z); Lt[c4 + 3][ii] = f2bf(v.w);
        }
        __syncthreads();
        const int nn = tid >> 2, ic0 = (tid & 3) * 16;
        #pragma unroll
        for (int k = 0; k < 4; ++k) {
            int ic = ic0 + k * 4;
            ushort4 o4;
            o4.x = Lt[nn][ic]; o4.y = Lt[nn][ic + 1];
            o4.z = Lt[nn][ic + 2]; o4.w = Lt[nn][ic + 3];
            *(ushort4*)&Bb[(size_t)(n0 + nn) * CIN + i0 + ic] = o4;
        }
    } else if (blk < 36) {
        // c rows: Bb[512+m][i], e = i*64+m (verified r3)
        const int i0 = (blk - 32) * 64;
        const float x0 = index[0], x1 = index[1], x2 = index[2], x3 = index[3];
        const int r = tid >> 4, c4 = (tid & 15) * 4;
        #pragma unroll
        for (int k = 0; k < 4; ++k) {
            int ii = r + k * 16;
            int e = (i0 + ii) * 64 + c4;
            float4 pb = *(const float4*)(fcwp_b + e);
            float4 ib = *(const float4*)(fcwi_b + e);
            float pbv[4] = {pb.x, pb.y, pb.z, pb.w};
            float ibv[4] = {ib.x, ib.y, ib.z, ib.w};
            #pragma unroll
            for (int j = 0; j < 4; ++j) {
                float4 wv = *(const float4*)(fcwi_w + (size_t)(e + j) * 4);
                Lt[c4 + j][ii] = f2bf(pbv[j] + ibv[j]
                    + x0 * wv.x + x1 * wv.y + x2 * wv.z + x3 * wv.w);
            }
        }
        __syncthreads();
        const int mm = tid >> 2, ic0 = (tid & 3) * 16;
        #pragma unroll
        for (int k = 0; k < 4; ++k) {
            int ic = ic0 + k * 4;
            ushort4 o4;
            o4.x = Lt[mm][ic]; o4.y = Lt[mm][ic + 1];
            o4.z = Lt[mm][ic + 2]; o4.w = Lt[mm][ic + 3];
            *(ushort4*)&Bb[(size_t)(512 + mm) * CIN + i0 + ic] = o4;
        }
    } else if (blk < 52) {
        // B2 cols [0,256) = target_w
        int base = (blk - 36) * 4096;
        #pragma unroll
        for (int k = 0; k < 4; ++k) {
            int e = base + k * 1024 + tid * 4;
            int o = e >> 8, c = e & 255;
            float4 v = *(const float4*)(target_w + e);
            ushort4 o4;
            o4.x = f2bf(v.x); o4.y = f2bf(v.y); o4.z = f2bf(v.z); o4.w = f2bf(v.w);
            *(ushort4*)&B2[(size_t)o * K2 + c] = o4;
        }
    } else if (blk < 56) {
        // B2 cols [256,320) = fcwe_w
        int base = (blk - 52) * 4096;
        #pragma unroll
        for (int k = 0; k < 4; ++k) {
            int e = base + k * 1024 + tid * 4;
            int o = e >> 6, m = e & 63;
            float4 v = *(const float4*)(fcwe_w + e);
            ushort4 o4;
            o4.x = f2bf(v.x); o4.y = f2bf(v.y); o4.z = f2bf(v.z); o4.w = f2bf(v.w);
            *(ushort4*)&B2[(size_t)o * K2 + 256 + m] = o4;
        }
    } else if (blk == 56) {
        // B2 tail per output o
        int o = tid;
        size_t bo = (size_t)o * K2;
        float4 p0 = *(const float4*)(fcbp_w + (size_t)o * 8);
        float4 p1 = *(const float4*)(fcbp_w + (size_t)o * 8 + 4);
        B2[bo + 320] = f2bf(p0.x); B2[bo + 321] = f2bf(p0.y);
        B2[bo + 322] = f2bf(p0.z); B2[bo + 323] = f2bf(p0.w);
        B2[bo + 324] = f2bf(p1.x); B2[bo + 325] = f2bf(p1.y);
        B2[bo + 326] = f2bf(p1.z); B2[bo + 327] = f2bf(p1.w);
        B2[bo + 328] = f2bf(fcwe_b[o]);
        float bc = target_b[o] + fcbp_b[o] + fcbi_b[o]
                 + index[0] * fcbi_w[o * 4]     + index[1] * fcbi_w[o * 4 + 1]
                 + index[2] * fcbi_w[o * 4 + 2] + index[3] * fcbi_w[o * 4 + 3];
        B2[bo + 329] = f2bf(bc);
        #pragma unroll
        for (int z = 330; z < K2; ++z) B2[bo + z] = 0;
    } else {
        // A2 rows [ (blk-57)*32 , +32 ): x cols, h cols, sx, ones, zero pad
        const int r0 = (blk - 57) * 32;
        const int rr = tid >> 3, cpos = tid & 7;
        const int b = r0 + rr;
        const float* xrow = x + (size_t)b * CIN;
        float psum = 0.f;
        #pragma unroll
        for (int k = 0; k < 8; ++k) {
            int c = (cpos + k * 8) * 4;
            float4 v = *(const float4*)(xrow + c);
            psum += v.x + v.y + v.z + v.w;
            ushort4 o4;
            o4.x = f2bf(v.x); o4.y = f2bf(v.y); o4.z = f2bf(v.z); o4.w = f2bf(v.w);
            *(ushort4*)&A2[(size_t)b * K2 + c] = o4;
        }
        red[rr][cpos] = psum;
        // h col (coalesced: thread tid reads h[r0*8+tid])
        A2[(size_t)b * K2 + 320 + cpos] = f2bf(h[(size_t)r0 * NP + tid]);
        // zero pad cols [330,352)
        for (int idx = tid; idx < 32 * 22; idx += 256) {
            int r2 = idx / 22, c2 = 330 + idx % 22;
            A2[(size_t)(r0 + r2) * K2 + c2] = 0;
        }
        __syncthreads();
        if (tid < 32) {
            float s = red[tid][0] + red[tid][1] + red[tid][2] + red[tid][3]
                    + red[tid][4] + red[tid][5] + red[tid][6] + red[tid][7];
            size_t base = (size_t)(r0 + tid) * K2;
            A2[base + 328] = f2bf(s);
            A2[base + 329] = 0x3F80;   // 1.0 bf16
        }
    }
}

// ---------------- gemm1: G = x_bf @ Bb^T ----------------
__global__ __launch_bounds__(256) void gemm1_kernel(
    const unsigned short* __restrict__ A2,   // x in cols [0,256), stride K2
    const unsigned short* __restrict__ Bb,   // [576][256]
    unsigned short* __restrict__ G)          // [2048][576] bf16
{
    __shared__ unsigned short As[64 * LDAS];
    __shared__ unsigned short Bs[64 * LDAS];

    const int tid = threadIdx.x, lane = tid & 63, w = tid >> 6;
    const int col = lane & 15, quad = lane >> 4;
    const int mb = blockIdx.x * 64, nb = blockIdx.y * 64;

    floatx4 acc[4] = {floatx4{0,0,0,0}, floatx4{0,0,0,0},
                      floatx4{0,0,0,0}, floatx4{0,0,0,0}};

    for (int kh = 0; kh < 2; ++kh) {
        const int k0 = kh * 128;
        __syncthreads();
        #pragma unroll
        for (int it = 0; it < 4; ++it) {
            int idx = it * 256 + tid;
            int r = idx >> 4, c = (idx & 15) * 8;
            *(uint4*)&As[r * LDAS + c] =
                *(const uint4*)(A2 + (size_t)(mb + r) * K2 + k0 + c);
            *(uint4*)&Bs[r * LDAS + c] =
                *(const uint4*)(Bb + (size_t)(nb + r) * CIN + k0 + c);
        }
        __syncthreads();
        #pragma unroll
        for (int ks = 0; ks < 4; ++ks) {
            int kc = ks * 32 + quad * 8;
            short8 af = *(const short8*)&As[(w * 16 + col) * LDAS + kc];
            #pragma unroll
            for (int f = 0; f < 4; ++f) {
                short8 bfr = *(const short8*)&Bs[(f * 16 + col) * LDAS + kc];
                acc[f] = __builtin_amdgcn_mfma_f32_16x16x32_bf16(af, bfr, acc[f], 0, 0, 0);
            }
        }
    }
    #pragma unroll
    for (int f = 0; f < 4; ++f)
        #pragma unroll
        for (int r = 0; r < 4; ++r)
            G[(size_t)(mb + w * 16 + quad * 4 + r) * LDG + nb + f * 16 + col]
                = f2bf(acc[f][r]);
}

// ---------------- gemm2: out = [x|t|h|sx|1] @ B2^T (t folded from G) --------
__global__ __launch_bounds__(256) void gemm2_kernel(
    const unsigned short* __restrict__ A2,   // [2048][352]
    const unsigned short* __restrict__ B2,   // [256][352]
    const unsigned short* __restrict__ G,    // [2048][576]
    float* __restrict__ out)                 // [2048][256]
{
    __shared__ unsigned short As[32 * LDA2S];   // 23040 B
    __shared__ unsigned short Bs[64 * LDB2S];   // 46080 B

    const int tid = threadIdx.x, lane = tid & 63, w = tid >> 6;
    const int col = lane & 15, quad = lane >> 4;
    const int b0 = blockIdx.x * 32, n0 = blockIdx.y * 64;

    // stage As x-cols [0,256)
    #pragma unroll
    for (int it = 0; it < 4; ++it) {
        int idx = it * 256 + tid;
        int r = idx >> 5, c = (idx & 31) * 8;
        *(uint4*)&As[r * LDA2S + c] =
            *(const uint4*)(A2 + (size_t)(b0 + r) * K2 + c);
    }
    // stage As cols [320,352)  (h | sx | 1 | zeros)
    if (tid < 128) {
        int r = tid >> 2, c = 320 + (tid & 3) * 8;
        *(uint4*)&As[r * LDA2S + c] =
            *(const uint4*)(A2 + (size_t)(b0 + r) * K2 + c);
    }
    // stage Bs 64 x 352
    #pragma unroll
    for (int it = 0; it < 11; ++it) {
        int idx = it * 256 + tid;
        int r = idx / 44, c = (idx % 44) * 8;
        *(uint4*)&Bs[r * LDB2S + c] =
            *(const uint4*)(B2 + (size_t)(n0 + r) * K2 + c);
    }
    // fold t[s][m] into As cols [256,320)
    {
        int s = tid >> 3, mg = tid & 7;
        const unsigned short* grow = G + (size_t)(b0 + s) * LDG;
        ushort4 hu0 = *(const ushort4*)(A2 + (size_t)(b0 + s) * K2 + 320);
        ushort4 hu1 = *(const ushort4*)(A2 + (size_t)(b0 + s) * K2 + 324);
        float hv[8] = {bf2f(hu0.x), bf2f(hu0.y), bf2f(hu0.z), bf2f(hu0.w),
                       bf2f(hu1.x), bf2f(hu1.y), bf2f(hu1.z), bf2f(hu1.w)};
        ushort4 cu0 = *(const ushort4*)(grow + 512 + mg * 8);
        ushort4 cu1 = *(const ushort4*)(grow + 512 + mg * 8 + 4);
        float t[8] = {bf2f(cu0.x), bf2f(cu0.y), bf2f(cu0.z), bf2f(cu0.w),
                      bf2f(cu1.x), bf2f(cu1.y), bf2f(cu1.z), bf2f(cu1.w)};
        #pragma unroll
        for (int j = 0; j < 8; ++j) {
            const unsigned short* gp = grow + (mg * 8 + j) * 8;
            ushort4 g0 = *(const ushort4*)gp;
            ushort4 g1 = *(const ushort4*)(gp + 4);
            t[j] += hv[0] * bf2f(g0.x) + hv[1] * bf2f(g0.y)
                  + hv[2] * bf2f(g0.z) + hv[3] * bf2f(g0.w)
                  + hv[4] * bf2f(g1.x) + hv[5] * bf2f(g1.y)
                  + hv[6] * bf2f(g1.z) + hv[7] * bf2f(g1.w);
        }
        ushort4 t0, t1;
        t0.x = f2bf(t[0]); t0.y = f2bf(t[1]); t0.z = f2bf(t[2]); t0.w = f2bf(t[3]);
        t1.x = f2bf(t[4]); t1.y = f2bf(t[5]); t1.z = f2bf(t[6]); t1.w = f2bf(t[7]);
        *(ushort4*)&As[s * LDA2S + 256 + mg * 8]     = t0;
        *(ushort4*)&As[s * LDA2S + 256 + mg * 8 + 4] = t1;
    }
    __syncthreads();

    const int mr = (w & 1) * 16, nbw = (w >> 1) * 32;
    floatx4 acc[2] = {floatx4{0,0,0,0}, floatx4{0,0,0,0}};
    #pragma unroll
    for (int ks = 0; ks < 11; ++ks) {
        int kc = ks * 32 + quad * 8;
        short8 af = *(const short8*)&As[(mr + col) * LDA2S + kc];
        #pragma unroll
        for (int f = 0; f < 2; ++f) {
            short8 bfr = *(const short8*)&Bs[(nbw + f * 16 + col) * LDB2S + kc];
            acc[f] = __builtin_amdgcn_mfma_f32_16x16x32_bf16(af, bfr, acc[f], 0, 0, 0);
        }
    }
    #pragma unroll
    for (int f = 0; f < 2; ++f)
        #pragma unroll
        for (int r = 0; r < 4; ++r)
            out[(size_t)(b0 + mr + quad * 4 + r) * COUT + n0 + nbw + f * 16 + col]
                = acc[f][r];
}

extern "C" void kernel_launch(void* const* d_in, const int* in_sizes, int n_in,
                              void* d_out, int out_size, void* d_ws, size_t ws_size,
                              hipStream_t stream) {
    const float* x        = (const float*)d_in[0];
    const float* h        = (const float*)d_in[1];
    const float* index    = (const float*)d_in[2];
    const float* target_w = (const float*)d_in[3];
    const float* target_b = (const float*)d_in[4];
    const float* fcwp_w   = (const float*)d_in[5];
    const float* fcwp_b   = (const float*)d_in[6];
    const float* fcwi_w   = (const float*)d_in[7];
    const float* fcwi_b   = (const float*)d_in[8];
    const float* fcwe_w   = (const float*)d_in[9];
    const float* fcwe_b   = (const float*)d_in[10];
    const float* fcbp_w   = (const float*)d_in[11];
    const float* fcbp_b   = (const float*)d_in[12];
    const float* fcbi_w   = (const float*)d_in[13];
    const float* fcbi_b   = (const float*)d_in[14];
    float* out = (float*)d_out;

    char* ws = (char*)d_ws;
    unsigned short* Bb = (unsigned short*)ws;               // 576*256*2  = 294912
    unsigned short* B2 = (unsigned short*)(ws + 294912);    // 256*352*2  = 180224
    unsigned short* A2 = (unsigned short*)(ws + 475136);    // 2048*352*2 = 1441792
    unsigned short* G  = (unsigned short*)(ws + 1916928);   // 2048*576*2 = 2359296

    setup_kernel<<<121, 256, 0, stream>>>(
        x, h, index, target_w, target_b, fcwp_w, fcwp_b, fcwi_w, fcwi_b,
        fcwe_w, fcwe_b, fcbp_w, fcbp_b, fcbi_w, fcbi_b, Bb, B2, A2);

    gemm1_kernel<<<dim3(B_TOT / 64, NB1 / 64), 256, 0, stream>>>(A2, Bb, G);

    gemm2_kernel<<<dim3(B_TOT / 32, COUT / 64), 256, 0, stream>>>(A2, B2, G, out);
}